// Round 2
// baseline (1710.011 us; speedup 1.0000x reference)
//
#include <hip/hip_runtime.h>

// Problem constants (B,T,C,NH fixed by the reference).
constexpr int kB  = 8;
constexpr int kT  = 1024;
constexpr int kC  = 768;
constexpr int kNH = 12;
constexpr int kHD = 64;          // C/NH
constexpr int kM  = kB * kT;     // 8192 rows
constexpr int k3C = 3 * kC;      // 2304

// out[M,N] = A[M,K] @ W[K,N] + bias[N].  fp32 everywhere.
// A has row stride lda (>= K).  M%64==0, N%64==0, K%16==0.
// Block = 256 threads, 64x64 output tile, K-tile = 16.
__global__ __launch_bounds__(256) void gemm_bias_kernel(
    const float* __restrict__ A, int lda,
    const float* __restrict__ W,
    const float* __restrict__ bias,
    float* __restrict__ out,
    int M, int N, int K)
{
    __shared__ float As[16][65];   // [k][m], +1 pad
    __shared__ float Bs[16][65];   // [k][n], +1 pad

    const int tid = threadIdx.x;
    const int tx = tid & 15, ty = tid >> 4;
    const int m0 = blockIdx.y * 64, n0 = blockIdx.x * 64;

    // A staging: thread -> (row ar, 4 consecutive k at ac)
    const int ar = tid >> 2;
    const int ac = (tid & 3) * 4;
    // W staging: thread -> (k-row brr, 4 consecutive n at bcc)
    const int brr = tid >> 4;
    const int bcc = (tid & 15) * 4;

    float acc[4][4] = {};

    for (int kt = 0; kt < K; kt += 16) {
        const float4 av = *(const float4*)(A + (size_t)(m0 + ar) * lda + kt + ac);
        As[ac + 0][ar] = av.x;
        As[ac + 1][ar] = av.y;
        As[ac + 2][ar] = av.z;
        As[ac + 3][ar] = av.w;
        const float4 wv = *(const float4*)(W + (size_t)(kt + brr) * N + n0 + bcc);
        Bs[brr][bcc + 0] = wv.x;
        Bs[brr][bcc + 1] = wv.y;
        Bs[brr][bcc + 2] = wv.z;
        Bs[brr][bcc + 3] = wv.w;
        __syncthreads();
        #pragma unroll
        for (int kk = 0; kk < 16; ++kk) {
            float a[4], b[4];
            #pragma unroll
            for (int i = 0; i < 4; ++i) a[i] = As[kk][ty * 4 + i];
            #pragma unroll
            for (int j = 0; j < 4; ++j) b[j] = Bs[kk][tx * 4 + j];
            #pragma unroll
            for (int i = 0; i < 4; ++i)
                #pragma unroll
                for (int j = 0; j < 4; ++j)
                    acc[i][j] = fmaf(a[i], b[j], acc[i][j]);
        }
        __syncthreads();
    }

    #pragma unroll
    for (int i = 0; i < 4; ++i) {
        const int m = m0 + ty * 4 + i;
        #pragma unroll
        for (int j = 0; j < 4; ++j) {
            const int n = n0 + tx * 4 + j;
            out[(size_t)m * N + n] = acc[i][j] + bias[n];
        }
    }
}

// Flash-style causal attention over qkv[B*T, 3C] (fp32).
// One wave per query row; 4 waves/block share (b,h) and K/V LDS chunks.
// Output y is written IN-PLACE into the Q columns of qkv:
//   y[b,t,h*64+d] -> qkv[(b*T+t)*3C + h*64 + d]
// Safe: that region is read (into LDS) only by its owning wave, before the
// same wave writes it at the end; K/V columns (offsets +C, +2C) are untouched.
__global__ __launch_bounds__(256) void attn_kernel(float* __restrict__ qkv)
{
    __shared__ float Ks[64][kHD + 1];
    __shared__ float Vs[64][kHD + 1];
    __shared__ float qs[4][kHD];
    __shared__ float ps[4][64];

    const int tid  = threadIdx.x;
    const int wid  = tid >> 6;
    const int lane = tid & 63;
    const int jb = blockIdx.x;
    const int bh = jb >> 8;                 // T/4 = 256 blocks per (b,h)
    const int b  = bh / kNH;
    const int h  = bh % kNH;
    const int t0 = (jb & 255) * 4;
    const int t  = t0 + wid;

    const float scale = 0.125f;             // 1/sqrt(64)

    // This wave's q row (pre-scaled) into LDS: lane <-> dim.
    qs[wid][lane] = qkv[(size_t)(b * kT + t) * k3C + h * kHD + lane] * scale;

    float m = -INFINITY, l = 0.f, o = 0.f;

    const int nchunks = (t0 + 4 + 63) >> 6;  // keys needed: 0..t0+3
    const int srow = tid >> 2;               // 0..63: staging row
    const int scol = (tid & 3) * 16;         // 16 consecutive dims

    for (int cidx = 0; cidx < nchunks; ++cidx) {
        const int kbase = cidx * 64;
        // Stage K,V chunk [64 keys][64 dims] (shared by all 4 waves).
        {
            const size_t rowbase =
                (size_t)(b * kT + kbase + srow) * k3C + h * kHD + scol;
            #pragma unroll
            for (int q4 = 0; q4 < 4; ++q4) {
                const float4 kv = *(const float4*)(qkv + rowbase + kC + q4 * 4);
                Ks[srow][scol + q4 * 4 + 0] = kv.x;
                Ks[srow][scol + q4 * 4 + 1] = kv.y;
                Ks[srow][scol + q4 * 4 + 2] = kv.z;
                Ks[srow][scol + q4 * 4 + 3] = kv.w;
                const float4 vv = *(const float4*)(qkv + rowbase + 2 * kC + q4 * 4);
                Vs[srow][scol + q4 * 4 + 0] = vv.x;
                Vs[srow][scol + q4 * 4 + 1] = vv.y;
                Vs[srow][scol + q4 * 4 + 2] = vv.z;
                Vs[srow][scol + q4 * 4 + 3] = vv.w;
            }
        }
        __syncthreads();

        // Phase A: lane j computes s_j = q . K[kbase+j]
        float s = 0.f;
        #pragma unroll 16
        for (int d = 0; d < kHD; ++d)
            s = fmaf(qs[wid][d], Ks[lane][d], s);
        if (kbase + lane > t) s = -INFINITY;

        float mc = s;
        #pragma unroll
        for (int off = 32; off > 0; off >>= 1)
            mc = fmaxf(mc, __shfl_xor(mc, off, 64));
        const float m_new = fmaxf(m, mc);
        const float alpha = __expf(m - m_new);   // m=-inf first chunk -> 0
        const float p = __expf(s - m_new);       // masked lanes -> 0
        float psum = p;
        #pragma unroll
        for (int off = 32; off > 0; off >>= 1)
            psum += __shfl_xor(psum, off, 64);
        l = l * alpha + psum;
        m = m_new;
        ps[wid][lane] = p;
        __syncthreads();

        // Phase B: lane d accumulates sum_j p_j * V[j][d]
        float acc = 0.f;
        #pragma unroll 16
        for (int j = 0; j < 64; ++j)
            acc = fmaf(ps[wid][j], Vs[j][lane], acc);
        o = o * alpha + acc;
        __syncthreads();
    }

    // Write y into the Q slot (column h*64+lane of the first C columns).
    qkv[(size_t)(b * kT + t) * k3C + h * kHD + lane] = o / l;
}

extern "C" void kernel_launch(void* const* d_in, const int* in_sizes, int n_in,
                              void* d_out, int out_size, void* d_ws, size_t ws_size,
                              hipStream_t stream) {
    const float* x      = (const float*)d_in[0];
    const float* w_attn = (const float*)d_in[1];
    const float* b_attn = (const float*)d_in[2];
    const float* w_proj = (const float*)d_in[3];
    const float* b_proj = (const float*)d_in[4];
    float* out = (float*)d_out;

    // Workspace: qkv[8192,2304] fp32 = 75.5 MB. Attention output y is
    // written in-place into qkv's Q columns (cols 0..767, row stride 2304).
    float* qkv = (float*)d_ws;

    // 1) QKV projection: [8192,768] @ [768,2304] + bias
    gemm_bias_kernel<<<dim3(k3C / 64, kM / 64), 256, 0, stream>>>(
        x, kC, w_attn, b_attn, qkv, kM, k3C, kC);

    // 2) Causal attention; y overwrites Q columns of qkv
    attn_kernel<<<kB * kNH * (kT / 4), 256, 0, stream>>>(qkv);

    // 3) Output projection: y(=qkv cols 0..767, lda=2304) @ w_proj + bias
    gemm_bias_kernel<<<dim3(kC / 64, kM / 64), 256, 0, stream>>>(
        qkv, k3C, w_proj, b_proj, out, kM, kC, kC);
}

// Round 3
// 1334.637 us; speedup vs baseline: 1.2813x; 1.2813x over previous
//
#include <hip/hip_runtime.h>

// Problem constants (B,T,C,NH fixed by the reference).
constexpr int kB  = 8;
constexpr int kT  = 1024;
constexpr int kC  = 768;
constexpr int kNH = 12;
constexpr int kHD = 64;          // C/NH
constexpr int kM  = kB * kT;     // 8192 rows
constexpr int k3C = 3 * kC;      // 2304

// out[M,N] = A[M,K] @ W[K,N] + bias[N].  fp32 everywhere.
// A has row stride lda (>= K).  M%64==0, N%64==0, K%16==0.
// Block = 256 threads, 64x64 output tile, K-tile = 16.
__global__ __launch_bounds__(256) void gemm_bias_kernel(
    const float* __restrict__ A, int lda,
    const float* __restrict__ W,
    const float* __restrict__ bias,
    float* __restrict__ out,
    int M, int N, int K)
{
    __shared__ float As[16][65];   // [k][m], +1 pad
    __shared__ float Bs[16][65];   // [k][n], +1 pad

    const int tid = threadIdx.x;
    const int tx = tid & 15, ty = tid >> 4;
    const int m0 = blockIdx.y * 64, n0 = blockIdx.x * 64;

    const int ar = tid >> 2;
    const int ac = (tid & 3) * 4;
    const int brr = tid >> 4;
    const int bcc = (tid & 15) * 4;

    float acc[4][4] = {};

    for (int kt = 0; kt < K; kt += 16) {
        const float4 av = *(const float4*)(A + (size_t)(m0 + ar) * lda + kt + ac);
        As[ac + 0][ar] = av.x;
        As[ac + 1][ar] = av.y;
        As[ac + 2][ar] = av.z;
        As[ac + 3][ar] = av.w;
        const float4 wv = *(const float4*)(W + (size_t)(kt + brr) * N + n0 + bcc);
        Bs[brr][bcc + 0] = wv.x;
        Bs[brr][bcc + 1] = wv.y;
        Bs[brr][bcc + 2] = wv.z;
        Bs[brr][bcc + 3] = wv.w;
        __syncthreads();
        #pragma unroll
        for (int kk = 0; kk < 16; ++kk) {
            float a[4], b[4];
            #pragma unroll
            for (int i = 0; i < 4; ++i) a[i] = As[kk][ty * 4 + i];
            #pragma unroll
            for (int j = 0; j < 4; ++j) b[j] = Bs[kk][tx * 4 + j];
            #pragma unroll
            for (int i = 0; i < 4; ++i)
                #pragma unroll
                for (int j = 0; j < 4; ++j)
                    acc[i][j] = fmaf(a[i], b[j], acc[i][j]);
        }
        __syncthreads();
    }

    #pragma unroll
    for (int i = 0; i < 4; ++i) {
        const int m = m0 + ty * 4 + i;
        #pragma unroll
        for (int j = 0; j < 4; ++j) {
            const int n = n0 + tx * 4 + j;
            out[(size_t)m * N + n] = acc[i][j] + bias[n];
        }
    }
}

// Flash-style causal attention over qkv[B*T, 3C] fp32.
// One block = 64 query rows of one (b,h). Register-blocked 4x4 micro-tiles
// for S=QK^T and O+=PV; online softmax kept in registers with __shfl_xor
// over the 16-lane row-groups (lanes sharing ty own the same 4 rows).
// Output y written in-place into the Q columns of qkv (safe: only this
// block ever touches Q cols of its own (b,h,t-range), staged before write).
// LDS layouts (no padding, 64 KB total = 2 blocks/CU):
//   QsT/KsT [d][row]: b128 compute reads hit distinct bank-quads.
//   Vs [j][d] row-major: reads 2-way (free).
//   Ps swizzled col' = (c+4r)&63: breaks ty-aliasing on PV row reads.
__global__ __launch_bounds__(256) void attn_kernel(float* __restrict__ qkv)
{
    __shared__ float QsT[kHD][64];   // [d][q-row]
    __shared__ float KsT[kHD][64];   // [d][k-row]
    __shared__ float Vs [64][kHD];   // [k-row][d]
    __shared__ float Ps [64][64];    // [q-row][col swizzled]

    const int tid = threadIdx.x;
    const int tx  = tid & 15;        // col group (cols 4tx..4tx+3)
    const int ty  = tid >> 4;        // row group (rows 4ty..4ty+3), 0..15
    const int bh  = blockIdx.x >> 4; // 16 q-tiles per (b,h)
    const int b   = bh / kNH;
    const int h   = bh % kNH;
    const int t0  = (blockIdx.x & 15) * 64;

    const int srow = tid >> 2;          // 0..63 staging row
    const int scol = (tid & 3) * 16;    // 16-float staging segment

    const float scale = 0.125f;         // 1/sqrt(64)

    // Stage Q^T (pre-scaled).
    {
        const size_t qbase = (size_t)(b * kT + t0 + srow) * k3C + h * kHD + scol;
        #pragma unroll
        for (int w = 0; w < 4; ++w) {
            const float4 v = *(const float4*)(qkv + qbase + 4 * w);
            QsT[scol + 4 * w + 0][srow] = v.x * scale;
            QsT[scol + 4 * w + 1][srow] = v.y * scale;
            QsT[scol + 4 * w + 2][srow] = v.z * scale;
            QsT[scol + 4 * w + 3][srow] = v.w * scale;
        }
    }

    float o[4][4] = {};
    float m_run[4], l_run[4];
    #pragma unroll
    for (int i = 0; i < 4; ++i) { m_run[i] = -INFINITY; l_run[i] = 0.f; }

    const int nchunks = t0 / 64 + 1;
    for (int c = 0; c < nchunks; ++c) {
        const int kbase = c * 64;
        __syncthreads();   // prev-iter PV reads done; also fences Q staging
        // Stage K^T and V for this 64-key chunk.
        {
            const size_t kb2 =
                (size_t)(b * kT + kbase + srow) * k3C + h * kHD + scol;
            #pragma unroll
            for (int w = 0; w < 4; ++w) {
                const float4 kv = *(const float4*)(qkv + kb2 + kC + 4 * w);
                KsT[scol + 4 * w + 0][srow] = kv.x;
                KsT[scol + 4 * w + 1][srow] = kv.y;
                KsT[scol + 4 * w + 2][srow] = kv.z;
                KsT[scol + 4 * w + 3][srow] = kv.w;
                *(float4*)&Vs[srow][scol + 4 * w] =
                    *(const float4*)(qkv + kb2 + 2 * kC + 4 * w);
            }
        }
        __syncthreads();

        // S = Q K^T : 4x4 micro-tile (rows 4ty+i, cols 4tx+j).
        float s[4][4] = {};
        #pragma unroll
        for (int d4 = 0; d4 < 16; ++d4) {
            float4 aT[4], bT[4];
            #pragma unroll
            for (int dd = 0; dd < 4; ++dd) {
                aT[dd] = *(const float4*)&QsT[4 * d4 + dd][4 * ty];
                bT[dd] = *(const float4*)&KsT[4 * d4 + dd][4 * tx];
            }
            #pragma unroll
            for (int dd = 0; dd < 4; ++dd) {
                const float a_[4] = {aT[dd].x, aT[dd].y, aT[dd].z, aT[dd].w};
                const float b_[4] = {bT[dd].x, bT[dd].y, bT[dd].z, bT[dd].w};
                #pragma unroll
                for (int i = 0; i < 4; ++i)
                    #pragma unroll
                    for (int j = 0; j < 4; ++j)
                        s[i][j] = fmaf(a_[i], b_[j], s[i][j]);
            }
        }

        // Causal mask: only the diagonal chunk (kbase == t0) needs it.
        if (kbase == t0) {
            #pragma unroll
            for (int i = 0; i < 4; ++i)
                #pragma unroll
                for (int j = 0; j < 4; ++j)
                    if (4 * tx + j > 4 * ty + i) s[i][j] = -INFINITY;
        }

        // Online softmax, stats in registers; row r=4ty+i shared by the
        // 16 contiguous lanes with equal ty -> shfl_xor 1/2/4/8.
        float alpha_[4];
        #pragma unroll
        for (int i = 0; i < 4; ++i) {
            float mc = fmaxf(fmaxf(s[i][0], s[i][1]), fmaxf(s[i][2], s[i][3]));
            mc = fmaxf(mc, __shfl_xor(mc, 1));
            mc = fmaxf(mc, __shfl_xor(mc, 2));
            mc = fmaxf(mc, __shfl_xor(mc, 4));
            mc = fmaxf(mc, __shfl_xor(mc, 8));
            const float m_new = fmaxf(m_run[i], mc);
            const float al = __expf(m_run[i] - m_new);  // first chunk: exp(-inf)=0
            float psum = 0.f;
            #pragma unroll
            for (int j = 0; j < 4; ++j) {
                s[i][j] = __expf(s[i][j] - m_new);      // masked: exp(-inf)=0
                psum += s[i][j];
            }
            psum += __shfl_xor(psum, 1);
            psum += __shfl_xor(psum, 2);
            psum += __shfl_xor(psum, 4);
            psum += __shfl_xor(psum, 8);
            m_run[i] = m_new;
            l_run[i] = l_run[i] * al + psum;
            alpha_[i] = al;
        }

        // Write P to LDS (swizzled: col c stored at (c+4r)&63).
        #pragma unroll
        for (int i = 0; i < 4; ++i) {
            const int r = 4 * ty + i;
            const int c0 = (4 * tx + 4 * r) & 63;
            float4 p4;
            p4.x = s[i][0]; p4.y = s[i][1]; p4.z = s[i][2]; p4.w = s[i][3];
            *(float4*)&Ps[r][c0] = p4;
        }
        __syncthreads();

        // O = O*alpha + P V : 4x4 micro-tile (rows 4ty+i, dims 4tx+j).
        #pragma unroll
        for (int i = 0; i < 4; ++i)
            #pragma unroll
            for (int j = 0; j < 4; ++j)
                o[i][j] *= alpha_[i];

        #pragma unroll
        for (int j4 = 0; j4 < 16; ++j4) {
            float4 p4[4], v4[4];
            #pragma unroll
            for (int i = 0; i < 4; ++i) {
                const int r = 4 * ty + i;
                p4[i] = *(const float4*)&Ps[r][(4 * j4 + 4 * r) & 63];
            }
            #pragma unroll
            for (int jj = 0; jj < 4; ++jj)
                v4[jj] = *(const float4*)&Vs[4 * j4 + jj][4 * tx];
            #pragma unroll
            for (int i = 0; i < 4; ++i) {
                const float p_[4] = {p4[i].x, p4[i].y, p4[i].z, p4[i].w};
                #pragma unroll
                for (int jj = 0; jj < 4; ++jj) {
                    o[i][0] = fmaf(p_[jj], v4[jj].x, o[i][0]);
                    o[i][1] = fmaf(p_[jj], v4[jj].y, o[i][1]);
                    o[i][2] = fmaf(p_[jj], v4[jj].z, o[i][2]);
                    o[i][3] = fmaf(p_[jj], v4[jj].w, o[i][3]);
                }
            }
        }
    }

    // y = O / l  -> written into the Q columns of qkv.
    #pragma unroll
    for (int i = 0; i < 4; ++i) {
        const float inv = 1.0f / l_run[i];
        const int t = t0 + 4 * ty + i;
        float4 r4;
        r4.x = o[i][0] * inv; r4.y = o[i][1] * inv;
        r4.z = o[i][2] * inv; r4.w = o[i][3] * inv;
        *(float4*)(qkv + (size_t)(b * kT + t) * k3C + h * kHD + 4 * tx) = r4;
    }
}

extern "C" void kernel_launch(void* const* d_in, const int* in_sizes, int n_in,
                              void* d_out, int out_size, void* d_ws, size_t ws_size,
                              hipStream_t stream) {
    const float* x      = (const float*)d_in[0];
    const float* w_attn = (const float*)d_in[1];
    const float* b_attn = (const float*)d_in[2];
    const float* w_proj = (const float*)d_in[3];
    const float* b_proj = (const float*)d_in[4];
    float* out = (float*)d_out;

    // Workspace: qkv[8192,2304] fp32 = 75.5 MB. Attention output y is
    // written in-place into qkv's Q columns (cols 0..767, row stride 2304).
    float* qkv = (float*)d_ws;

    // 1) QKV projection: [8192,768] @ [768,2304] + bias
    gemm_bias_kernel<<<dim3(k3C / 64, kM / 64), 256, 0, stream>>>(
        x, kC, w_attn, b_attn, qkv, kM, k3C, kC);

    // 2) Causal attention; y overwrites Q columns of qkv
    attn_kernel<<<kB * kNH * (kT / 64), 256, 0, stream>>>(qkv);

    // 3) Output projection: y(=qkv cols 0..767, lda=2304) @ w_proj + bias
    gemm_bias_kernel<<<dim3(kC / 64, kM / 64), 256, 0, stream>>>(
        qkv, k3C, w_proj, b_proj, out, kM, kC, kC);
}

// Round 5
// 748.713 us; speedup vs baseline: 2.2839x; 1.7826x over previous
//
#include <hip/hip_runtime.h>

// Problem constants (B,T,C,NH fixed by the reference).
constexpr int kB  = 8;
constexpr int kT  = 1024;
constexpr int kC  = 768;
constexpr int kNH = 12;
constexpr int kHD = 64;          // C/NH
constexpr int kM  = kB * kT;     // 8192 rows
constexpr int k3C = 3 * kC;      // 2304

using bf16x8 = __attribute__((ext_vector_type(8))) __bf16;
using f32x4  = __attribute__((ext_vector_type(4))) float;

__device__ __forceinline__ float bf2f(unsigned short u) {
    union { unsigned int i; float f; } v;
    v.i = ((unsigned int)u) << 16;
    return v.f;
}

// fp32 -> bf16 round-to-nearest-even.
__device__ __forceinline__ unsigned short f2bf(float f) {
    union { float f; unsigned int u; } v; v.f = f;
    unsigned int r = v.u + 0x7fffu + ((v.u >> 16) & 1u);
    return (unsigned short)(r >> 16);
}

__device__ __forceinline__ void unpack8(float* dst, uint4 v) {
    dst[0] = bf2f((unsigned short)(v.x & 0xffffu));
    dst[1] = bf2f((unsigned short)(v.x >> 16));
    dst[2] = bf2f((unsigned short)(v.y & 0xffffu));
    dst[3] = bf2f((unsigned short)(v.y >> 16));
    dst[4] = bf2f((unsigned short)(v.z & 0xffffu));
    dst[5] = bf2f((unsigned short)(v.z >> 16));
    dst[6] = bf2f((unsigned short)(v.w & 0xffffu));
    dst[7] = bf2f((unsigned short)(v.w >> 16));
}

// Async global->LDS, 16 B/lane. lptr MUST be the wave-uniform base; HW
// writes lane i at lptr + i*16 (m104/m108). Pass base, not base+lane off.
__device__ __forceinline__ void async16(const void* g, void* l) {
    __builtin_amdgcn_global_load_lds(
        (__attribute__((address_space(1))) void*)g,
        (__attribute__((address_space(3))) void*)l, 16, 0, 0);
}

// Explicit drain of LDS-DMA before barrier: global_load_lds has no dest
// VGPR, so we do not rely on the compiler's pre-barrier waitcnt covering
// it (suspected source of round-4's rare replay divergence).
// imm encoding (gfx9): vmcnt[3:0]=0, expcnt[6:4]=7, lgkmcnt[11:8]=15.
__device__ __forceinline__ void wait_vm0() {
    __builtin_amdgcn_s_waitcnt(0x0F70);
}

// ---------------- pre-passes ----------------

// fp32 -> bf16 elementwise (n divisible by 4*256).
__global__ __launch_bounds__(256) void cvt_bf16_kernel(
    const float* __restrict__ in, unsigned short* __restrict__ out)
{
    const int i = blockIdx.x * 256 + threadIdx.x;
    const float4 v = ((const float4*)in)[i];
    ushort4 o;
    o.x = f2bf(v.x); o.y = f2bf(v.y); o.z = f2bf(v.z); o.w = f2bf(v.w);
    ((ushort4*)out)[i] = o;
}

// W[K][N] fp32 -> Wt[N][K] bf16.  Grid (N/32, K/32), block 256 (32x8).
__global__ __launch_bounds__(256) void transpose_cvt_kernel(
    const float* __restrict__ W, unsigned short* __restrict__ Wt, int K, int N)
{
    __shared__ float tile[32][33];
    const int tx = threadIdx.x & 31, ty = threadIdx.x >> 5;
    const int n0 = blockIdx.x * 32, k0 = blockIdx.y * 32;
    #pragma unroll
    for (int i = 0; i < 4; ++i)
        tile[ty + i * 8][tx] = W[(size_t)(k0 + ty + i * 8) * N + n0 + tx];
    __syncthreads();
    #pragma unroll
    for (int i = 0; i < 4; ++i)
        Wt[(size_t)(n0 + ty + i * 8) * K + k0 + tx] = f2bf(tile[tx][ty + i * 8]);
}

// ---------------- MFMA GEMM ----------------
// out[M,N] = A[M,K](bf16, row stride lda) @ Bt[N,K](bf16)^T + bias(fp32).
// 128x128 tile, BK=64, 256 threads (4 waves, 2x2 of 64x64 each).
// LDS in MFMA fragment order: subtile (ki,si) = 16 rows x 32 k, stored as
// 64 lanes x 8 bf16 contiguous (lane l <-> [row l&15][k (l>>4)*8..+7]) so
// global_load_lds(16B, wave-uniform base) staging and ds_read_b128
// fragment reads are both lane-sequential (conflict-free).
template<bool OUT_BF16>
__global__ __launch_bounds__(256) void gemm_mfma_kernel(
    const unsigned short* __restrict__ A, int lda,
    const unsigned short* __restrict__ Bt,
    const float* __restrict__ bias,
    void* __restrict__ outv, int N, int K)
{
    alignas(16) __shared__ unsigned short As[16 * 512];  // 16 KB
    alignas(16) __shared__ unsigned short Bs[16 * 512];  // 16 KB

    const int tid  = threadIdx.x;
    const int w    = tid >> 6;
    const int lane = tid & 63;
    const int wr = w >> 1, wc = w & 1;
    const int m0 = blockIdx.y * 128, n0 = blockIdx.x * 128;

    const int fr = lane & 15;            // row within 16-row subtile
    const int fk = (lane >> 4) * 8;      // k offset within 32-k subtile

    f32x4 acc[4][4];
    #pragma unroll
    for (int i = 0; i < 4; ++i)
        #pragma unroll
        for (int j = 0; j < 4; ++j) {
            f32x4 z = {0.f, 0.f, 0.f, 0.f};
            acc[i][j] = z;
        }

    for (int kt = 0; kt < K; kt += 64) {
        #pragma unroll
        for (int t = 0; t < 4; ++t) {
            const int fa = w * 4 + t;            // fragment tile 0..15
            const int ki = fa >> 3, si = fa & 7; // k-subtile, m/n-subtile
            const unsigned short* ga =
                A + (size_t)(m0 + si * 16 + fr) * lda + kt + ki * 32 + fk;
            async16(ga, &As[fa * 512]);          // wave-uniform LDS base
            const unsigned short* gb =
                Bt + (size_t)(n0 + si * 16 + fr) * K + kt + ki * 32 + fk;
            async16(gb, &Bs[fa * 512]);
        }
        wait_vm0();        // drain LDS-DMA explicitly
        __syncthreads();

        #pragma unroll
        for (int ki = 0; ki < 2; ++ki) {
            bf16x8 a[4], b[4];
            #pragma unroll
            for (int i = 0; i < 4; ++i)
                a[i] = *(const bf16x8*)&As[(ki * 8 + wr * 4 + i) * 512 + lane * 8];
            #pragma unroll
            for (int j = 0; j < 4; ++j)
                b[j] = *(const bf16x8*)&Bs[(ki * 8 + wc * 4 + j) * 512 + lane * 8];
            #pragma unroll
            for (int i = 0; i < 4; ++i)
                #pragma unroll
                for (int j = 0; j < 4; ++j)
                    acc[i][j] = __builtin_amdgcn_mfma_f32_16x16x32_bf16(
                        a[i], b[j], acc[i][j], 0, 0, 0);
        }
        __syncthreads();
    }

    // Epilogue.  C/D: col = lane&15, row = (lane>>4)*4 + reg.
    const int quad  = lane >> 4;
    const int col16 = lane & 15;
    float biasv[4];
    #pragma unroll
    for (int j = 0; j < 4; ++j)
        biasv[j] = bias[n0 + wc * 64 + j * 16 + col16];

    #pragma unroll
    for (int i = 0; i < 4; ++i) {
        #pragma unroll
        for (int r = 0; r < 4; ++r) {
            const int row = m0 + wr * 64 + i * 16 + quad * 4 + r;
            #pragma unroll
            for (int j = 0; j < 4; ++j) {
                const int col = n0 + wc * 64 + j * 16 + col16;
                const float v = acc[i][j][r] + biasv[j];
                if (OUT_BF16)
                    ((unsigned short*)outv)[(size_t)row * N + col] = f2bf(v);
                else
                    ((float*)outv)[(size_t)row * N + col] = v;
            }
        }
    }
}

// ---------------- attention (fp32 compute, bf16 in/out) ----------------
// One block = 64 query rows of one (b,h); 4x4 register micro-tiles; online
// softmax in registers. qkv bf16 [B*T,3C]; y bf16 [B*T,C] separate buffer.
__global__ __launch_bounds__(256) void attn_kernel(
    const unsigned short* __restrict__ qkv, unsigned short* __restrict__ y)
{
    __shared__ float QsT[kHD][64];   // [d][q-row]
    __shared__ float KsT[kHD][64];   // [d][k-row]
    __shared__ float Vs [64][kHD];   // [k-row][d]
    __shared__ float Ps [64][64];    // [q-row][col swizzled]

    const int tid = threadIdx.x;
    const int tx  = tid & 15;
    const int ty  = tid >> 4;
    const int bh  = blockIdx.x >> 4;
    const int b   = bh / kNH;
    const int h   = bh % kNH;
    const int t0  = (blockIdx.x & 15) * 64;

    const int srow = tid >> 2;
    const int scol = (tid & 3) * 16;

    const float scale = 0.125f;

    // Stage Q^T (pre-scaled).
    {
        const size_t qbase = (size_t)(b * kT + t0 + srow) * k3C + h * kHD + scol;
        float tmp[16];
        unpack8(tmp,     *(const uint4*)(qkv + qbase));
        unpack8(tmp + 8, *(const uint4*)(qkv + qbase + 8));
        #pragma unroll
        for (int u = 0; u < 16; ++u)
            QsT[scol + u][srow] = tmp[u] * scale;
    }

    float o[4][4] = {};
    float m_run[4], l_run[4];
    #pragma unroll
    for (int i = 0; i < 4; ++i) { m_run[i] = -INFINITY; l_run[i] = 0.f; }

    const int nchunks = t0 / 64 + 1;
    for (int c = 0; c < nchunks; ++c) {
        const int kbase = c * 64;
        __syncthreads();   // prev-iter PV reads done; also fences Q staging
        {
            const size_t kb2 =
                (size_t)(b * kT + kbase + srow) * k3C + h * kHD + scol;
            float tmp[16];
            unpack8(tmp,     *(const uint4*)(qkv + kb2 + kC));
            unpack8(tmp + 8, *(const uint4*)(qkv + kb2 + kC + 8));
            #pragma unroll
            for (int u = 0; u < 16; ++u)
                KsT[scol + u][srow] = tmp[u];
            unpack8(tmp,     *(const uint4*)(qkv + kb2 + 2 * kC));
            unpack8(tmp + 8, *(const uint4*)(qkv + kb2 + 2 * kC + 8));
            #pragma unroll
            for (int u = 0; u < 16; ++u)
                Vs[srow][scol + u] = tmp[u];
        }
        __syncthreads();

        // S = Q K^T : 4x4 micro-tile (rows 4ty+i, cols 4tx+j).
        float s[4][4] = {};
        #pragma unroll
        for (int d4 = 0; d4 < 16; ++d4) {
            float4 aT[4], bT[4];
            #pragma unroll
            for (int dd = 0; dd < 4; ++dd) {
                aT[dd] = *(const float4*)&QsT[4 * d4 + dd][4 * ty];
                bT[dd] = *(const float4*)&KsT[4 * d4 + dd][4 * tx];
            }
            #pragma unroll
            for (int dd = 0; dd < 4; ++dd) {
                const float a_[4] = {aT[dd].x, aT[dd].y, aT[dd].z, aT[dd].w};
                const float b_[4] = {bT[dd].x, bT[dd].y, bT[dd].z, bT[dd].w};
                #pragma unroll
                for (int i = 0; i < 4; ++i)
                    #pragma unroll
                    for (int j = 0; j < 4; ++j)
                        s[i][j] = fmaf(a_[i], b_[j], s[i][j]);
            }
        }

        if (kbase == t0) {
            #pragma unroll
            for (int i = 0; i < 4; ++i)
                #pragma unroll
                for (int j = 0; j < 4; ++j)
                    if (4 * tx + j > 4 * ty + i) s[i][j] = -INFINITY;
        }

        float alpha_[4];
        #pragma unroll
        for (int i = 0; i < 4; ++i) {
            float mc = fmaxf(fmaxf(s[i][0], s[i][1]), fmaxf(s[i][2], s[i][3]));
            mc = fmaxf(mc, __shfl_xor(mc, 1));
            mc = fmaxf(mc, __shfl_xor(mc, 2));
            mc = fmaxf(mc, __shfl_xor(mc, 4));
            mc = fmaxf(mc, __shfl_xor(mc, 8));
            const float m_new = fmaxf(m_run[i], mc);
            const float al = __expf(m_run[i] - m_new);
            float psum = 0.f;
            #pragma unroll
            for (int j = 0; j < 4; ++j) {
                s[i][j] = __expf(s[i][j] - m_new);
                psum += s[i][j];
            }
            psum += __shfl_xor(psum, 1);
            psum += __shfl_xor(psum, 2);
            psum += __shfl_xor(psum, 4);
            psum += __shfl_xor(psum, 8);
            m_run[i] = m_new;
            l_run[i] = l_run[i] * al + psum;
            alpha_[i] = al;
        }

        #pragma unroll
        for (int i = 0; i < 4; ++i) {
            const int r = 4 * ty + i;
            const int c0 = (4 * tx + 4 * r) & 63;
            float4 p4;
            p4.x = s[i][0]; p4.y = s[i][1]; p4.z = s[i][2]; p4.w = s[i][3];
            *(float4*)&Ps[r][c0] = p4;
        }
        __syncthreads();

        #pragma unroll
        for (int i = 0; i < 4; ++i)
            #pragma unroll
            for (int j = 0; j < 4; ++j)
                o[i][j] *= alpha_[i];

        #pragma unroll
        for (int j4 = 0; j4 < 16; ++j4) {
            float4 p4[4], v4[4];
            #pragma unroll
            for (int i = 0; i < 4; ++i) {
                const int r = 4 * ty + i;
                p4[i] = *(const float4*)&Ps[r][(4 * j4 + 4 * r) & 63];
            }
            #pragma unroll
            for (int jj = 0; jj < 4; ++jj)
                v4[jj] = *(const float4*)&Vs[4 * j4 + jj][4 * tx];
            #pragma unroll
            for (int i = 0; i < 4; ++i) {
                const float p_[4] = {p4[i].x, p4[i].y, p4[i].z, p4[i].w};
                #pragma unroll
                for (int jj = 0; jj < 4; ++jj) {
                    o[i][0] = fmaf(p_[jj], v4[jj].x, o[i][0]);
                    o[i][1] = fmaf(p_[jj], v4[jj].y, o[i][1]);
                    o[i][2] = fmaf(p_[jj], v4[jj].z, o[i][2]);
                    o[i][3] = fmaf(p_[jj], v4[jj].w, o[i][3]);
                }
            }
        }
    }

    // y = O / l -> bf16, separate buffer [B*T, C].
    #pragma unroll
    for (int i = 0; i < 4; ++i) {
        const float inv = 1.0f / l_run[i];
        const int t = t0 + 4 * ty + i;
        ushort4 r4;
        r4.x = f2bf(o[i][0] * inv); r4.y = f2bf(o[i][1] * inv);
        r4.z = f2bf(o[i][2] * inv); r4.w = f2bf(o[i][3] * inv);
        *(ushort4*)(y + (size_t)(b * kT + t) * kC + h * kHD + 4 * tx) = r4;
    }
}

extern "C" void kernel_launch(void* const* d_in, const int* in_sizes, int n_in,
                              void* d_out, int out_size, void* d_ws, size_t ws_size,
                              hipStream_t stream) {
    const float* x      = (const float*)d_in[0];
    const float* w_attn = (const float*)d_in[1];
    const float* b_attn = (const float*)d_in[2];
    const float* w_proj = (const float*)d_in[3];
    const float* b_proj = (const float*)d_in[4];
    float* out = (float*)d_out;

    // Workspace (bf16 buffers, 64.5 MiB total):
    unsigned short* xb     = (unsigned short*)d_ws;           // [8192][768]
    unsigned short* wattnT = xb     + (size_t)kM * kC;        // [2304][768]
    unsigned short* wprojT = wattnT + (size_t)k3C * kC;       // [768][768]
    unsigned short* qkv    = wprojT + (size_t)kC * kC;        // [8192][2304]
    unsigned short* yb     = qkv    + (size_t)kM * k3C;       // [8192][768]

    // Pre-passes: cast x; transpose+cast weights to [N][K].
    cvt_bf16_kernel<<<(kM * kC) / (4 * 256), 256, 0, stream>>>(x, xb);
    transpose_cvt_kernel<<<dim3(k3C / 32, kC / 32), 256, 0, stream>>>(
        w_attn, wattnT, kC, k3C);
    transpose_cvt_kernel<<<dim3(kC / 32, kC / 32), 256, 0, stream>>>(
        w_proj, wprojT, kC, kC);

    // 1) QKV projection: xb[8192,768] @ wattnT^T + b_attn -> qkv (bf16)
    gemm_mfma_kernel<true><<<dim3(k3C / 128, kM / 128), 256, 0, stream>>>(
        xb, kC, wattnT, b_attn, qkv, k3C, kC);

    // 2) Causal attention -> yb (bf16)
    attn_kernel<<<kB * kNH * (kT / 64), 256, 0, stream>>>(qkv, yb);

    // 3) Output projection: yb @ wprojT^T + b_proj -> out (fp32)
    gemm_mfma_kernel<false><<<dim3(kC / 128, kM / 128), 256, 0, stream>>>(
        yb, kC, wprojT, b_proj, out, kC, kC);
}

// Round 6
// 283.469 us; speedup vs baseline: 6.0324x; 2.6412x over previous
//
#include <hip/hip_runtime.h>

// Problem constants (B,T,C,NH fixed by the reference).
constexpr int kB  = 8;
constexpr int kT  = 1024;
constexpr int kC  = 768;
constexpr int kNH = 12;
constexpr int kHD = 64;          // C/NH
constexpr int kM  = kB * kT;     // 8192 rows
constexpr int k3C = 3 * kC;      // 2304

using bf16x8 = __attribute__((ext_vector_type(8))) __bf16;
using f32x4  = __attribute__((ext_vector_type(4))) float;

__device__ __forceinline__ float bf2f(unsigned short u) {
    union { unsigned int i; float f; } v;
    v.i = ((unsigned int)u) << 16;
    return v.f;
}

// fp32 -> bf16 round-to-nearest-even.
__device__ __forceinline__ unsigned short f2bf(float f) {
    union { float f; unsigned int u; } v; v.f = f;
    unsigned int r = v.u + 0x7fffu + ((v.u >> 16) & 1u);
    return (unsigned short)(r >> 16);
}

// Async global->LDS, 16 B/lane. LDS arg must be the wave-uniform base; HW
// writes lane i at base + i*16 (m104/m108).
__device__ __forceinline__ void async16(const void* g, void* l) {
    __builtin_amdgcn_global_load_lds(
        (__attribute__((address_space(1))) void*)g,
        (__attribute__((address_space(3))) void*)l, 16, 0, 0);
}

// Explicit LDS-DMA drain before barrier (round-5 determinism fix — keep).
// imm: vmcnt[3:0]=0, expcnt[6:4]=7, lgkmcnt[11:8]=15.
__device__ __forceinline__ void wait_vm0() {
    __builtin_amdgcn_s_waitcnt(0x0F70);
}

// ---------------- pre-passes ----------------

// fp32 -> bf16 elementwise (n divisible by 4*256).
__global__ __launch_bounds__(256) void cvt_bf16_kernel(
    const float* __restrict__ in, unsigned short* __restrict__ out)
{
    const int i = blockIdx.x * 256 + threadIdx.x;
    const float4 v = ((const float4*)in)[i];
    ushort4 o;
    o.x = f2bf(v.x); o.y = f2bf(v.y); o.z = f2bf(v.z); o.w = f2bf(v.w);
    ((ushort4*)out)[i] = o;
}

// W[K][N] fp32 -> Wt[N][K] bf16.  Grid (N/32, K/32), block 256 (32x8).
__global__ __launch_bounds__(256) void transpose_cvt_kernel(
    const float* __restrict__ W, unsigned short* __restrict__ Wt, int K, int N)
{
    __shared__ float tile[32][33];
    const int tx = threadIdx.x & 31, ty = threadIdx.x >> 5;
    const int n0 = blockIdx.x * 32, k0 = blockIdx.y * 32;
    #pragma unroll
    for (int i = 0; i < 4; ++i)
        tile[ty + i * 8][tx] = W[(size_t)(k0 + ty + i * 8) * N + n0 + tx];
    __syncthreads();
    #pragma unroll
    for (int i = 0; i < 4; ++i)
        Wt[(size_t)(n0 + ty + i * 8) * K + k0 + tx] = f2bf(tile[tx][ty + i * 8]);
}

// V columns of qkv -> VT[bh][d][t] (bf16).  One block = 64t x 64d of one
// (b,h).  Grid 96*16.
__global__ __launch_bounds__(256) void vtrans_kernel(
    const unsigned short* __restrict__ qkv, unsigned short* __restrict__ VT)
{
    __shared__ unsigned short tile[64][72];   // 144 B rows (16B-aligned)
    const int tid = threadIdx.x;
    const int bh = blockIdx.x >> 4;
    const int b = bh / kNH, h = bh % kNH;
    const int tt = (blockIdx.x & 15) * 64;
    const int row = tid >> 2;
    const int c0  = (tid & 3) * 16;
    const unsigned short* src =
        qkv + (size_t)(b * kT + tt + row) * k3C + 2 * kC + h * kHD + c0;
    *(uint4*)&tile[row][c0]     = *(const uint4*)src;
    *(uint4*)&tile[row][c0 + 8] = *(const uint4*)(src + 8);
    __syncthreads();
    const int d  = tid >> 2;
    const int t8 = (tid & 3) * 16;
    unsigned short tmp[16];
    #pragma unroll
    for (int i = 0; i < 16; ++i) tmp[i] = tile[t8 + i][d];
    unsigned short* dst = VT + ((size_t)bh * kHD + d) * kT + tt + t8;
    *(uint4*)dst       = *(uint4*)&tmp[0];
    *(uint4*)(dst + 8) = *(uint4*)&tmp[8];
}

// ---------------- MFMA GEMM ----------------
// out[M,N] = A[M,K](bf16, row stride lda) @ Bt[N,K](bf16)^T + bias(fp32).
// 128x128 tile, BK=64, 256 threads (4 waves, 2x2 of 64x64 each).
template<bool OUT_BF16>
__global__ __launch_bounds__(256) void gemm_mfma_kernel(
    const unsigned short* __restrict__ A, int lda,
    const unsigned short* __restrict__ Bt,
    const float* __restrict__ bias,
    void* __restrict__ outv, int N, int K)
{
    alignas(16) __shared__ unsigned short As[16 * 512];  // 16 KB
    alignas(16) __shared__ unsigned short Bs[16 * 512];  // 16 KB

    const int tid  = threadIdx.x;
    const int w    = tid >> 6;
    const int lane = tid & 63;
    const int wr = w >> 1, wc = w & 1;
    const int m0 = blockIdx.y * 128, n0 = blockIdx.x * 128;

    const int fr = lane & 15;            // row within 16-row subtile
    const int fk = (lane >> 4) * 8;      // k offset within 32-k subtile

    f32x4 acc[4][4];
    #pragma unroll
    for (int i = 0; i < 4; ++i)
        #pragma unroll
        for (int j = 0; j < 4; ++j) {
            f32x4 z = {0.f, 0.f, 0.f, 0.f};
            acc[i][j] = z;
        }

    for (int kt = 0; kt < K; kt += 64) {
        #pragma unroll
        for (int t = 0; t < 4; ++t) {
            const int fa = w * 4 + t;            // fragment tile 0..15
            const int ki = fa >> 3, si = fa & 7; // k-subtile, m/n-subtile
            const unsigned short* ga =
                A + (size_t)(m0 + si * 16 + fr) * lda + kt + ki * 32 + fk;
            async16(ga, &As[fa * 512]);          // wave-uniform LDS base
            const unsigned short* gb =
                Bt + (size_t)(n0 + si * 16 + fr) * K + kt + ki * 32 + fk;
            async16(gb, &Bs[fa * 512]);
        }
        wait_vm0();
        __syncthreads();

        #pragma unroll
        for (int ki = 0; ki < 2; ++ki) {
            bf16x8 a[4], b[4];
            #pragma unroll
            for (int i = 0; i < 4; ++i)
                a[i] = *(const bf16x8*)&As[(ki * 8 + wr * 4 + i) * 512 + lane * 8];
            #pragma unroll
            for (int j = 0; j < 4; ++j)
                b[j] = *(const bf16x8*)&Bs[(ki * 8 + wc * 4 + j) * 512 + lane * 8];
            #pragma unroll
            for (int i = 0; i < 4; ++i)
                #pragma unroll
                for (int j = 0; j < 4; ++j)
                    acc[i][j] = __builtin_amdgcn_mfma_f32_16x16x32_bf16(
                        a[i], b[j], acc[i][j], 0, 0, 0);
        }
        __syncthreads();
    }

    // Epilogue.  C/D: col = lane&15, row = (lane>>4)*4 + reg.
    const int quad  = lane >> 4;
    const int col16 = lane & 15;
    float biasv[4];
    #pragma unroll
    for (int j = 0; j < 4; ++j)
        biasv[j] = bias[n0 + wc * 64 + j * 16 + col16];

    #pragma unroll
    for (int i = 0; i < 4; ++i) {
        #pragma unroll
        for (int r = 0; r < 4; ++r) {
            const int row = m0 + wr * 64 + i * 16 + quad * 4 + r;
            #pragma unroll
            for (int j = 0; j < 4; ++j) {
                const int col = n0 + wc * 64 + j * 16 + col16;
                const float v = acc[i][j][r] + biasv[j];
                if (OUT_BF16)
                    ((unsigned short*)outv)[(size_t)row * N + col] = f2bf(v);
                else
                    ((float*)outv)[(size_t)row * N + col] = v;
            }
        }
    }
}

// ---------------- MFMA flash attention ----------------
// One block = 64 query rows of one (b,h); 4 waves; wave w owns q-subtile w
// (16 rows).  S=QK^T and O+=PV on the matrix pipe (16x16x32 bf16 MFMA);
// online softmax in registers (shfl_xor over quad groups).  All LDS in
// fragment order (1 KB frags): async16 staging + ds_read_b128, both
// lane-sequential.  P round-trips through a WAVE-PRIVATE frag (m120
// layout transform), so no barrier between P write and read.
__global__ __launch_bounds__(256) void attn_mfma_kernel(
    const unsigned short* __restrict__ qkv,
    const unsigned short* __restrict__ VT,     // [96][64][1024]
    unsigned short* __restrict__ y)            // [8192][768]
{
    alignas(16) __shared__ unsigned short Qf[8 * 512];  // (qsub*2+dsub)
    alignas(16) __shared__ unsigned short Kf[8 * 512];  // (ksub*2+dsub)
    alignas(16) __shared__ unsigned short Vf[8 * 512];  // (nsub*2+kk)
    alignas(16) __shared__ unsigned short Pf[8 * 512];  // (qsub*2+kk), wave-private

    const int tid  = threadIdx.x;
    const int w    = tid >> 6;
    const int lane = tid & 63;
    const int quad = lane >> 4, l15 = lane & 15;
    const int bh = blockIdx.x >> 4;
    const int b  = bh / kNH, h = bh % kNH;
    const int t0 = (15 - (blockIdx.x & 15)) * 64;   // heavy q-tiles first

    // Stage Q frags for this wave's 16 query rows (read only by wave w).
    {
        const unsigned short* g0 =
            qkv + (size_t)(b * kT + t0 + w * 16 + l15) * k3C + h * kHD + quad * 8;
        async16(g0,      &Qf[(w * 2 + 0) * 512]);
        async16(g0 + 32, &Qf[(w * 2 + 1) * 512]);
    }

    float m_run[4], l_run[4];
    f32x4 acc_o[4];
    #pragma unroll
    for (int r = 0; r < 4; ++r) { m_run[r] = -INFINITY; l_run[r] = 0.f; }
    #pragma unroll
    for (int n = 0; n < 4; ++n) {
        f32x4 z = {0.f, 0.f, 0.f, 0.f};
        acc_o[n] = z;
    }

    const int nchunks = t0 / 64 + 1;
    for (int c = 0; c < nchunks; ++c) {
        const int kbase = c * 64;
        __syncthreads();   // prev chunk's Kf/Vf reads complete
        // Wave w stages K frags (ksub=w) and V^T frags (nsub=w).
        {
            const unsigned short* gk = qkv +
                (size_t)(b * kT + kbase + w * 16 + l15) * k3C + kC + h * kHD + quad * 8;
            async16(gk,      &Kf[(w * 2 + 0) * 512]);
            async16(gk + 32, &Kf[(w * 2 + 1) * 512]);
            const unsigned short* gv = VT +
                ((size_t)bh * kHD + w * 16 + l15) * kT + kbase + quad * 8;
            async16(gv,      &Vf[(w * 2 + 0) * 512]);
            async16(gv + 32, &Vf[(w * 2 + 1) * 512]);
        }
        wait_vm0();
        __syncthreads();

        // S = Q K^T  (D[m=q][n=key]); 8 MFMAs.
        f32x4 acc_s[4];
        #pragma unroll
        for (int k = 0; k < 4; ++k) {
            f32x4 z = {0.f, 0.f, 0.f, 0.f};
            acc_s[k] = z;
        }
        const bf16x8 aq0 = *(const bf16x8*)&Qf[(w * 2 + 0) * 512 + lane * 8];
        const bf16x8 aq1 = *(const bf16x8*)&Qf[(w * 2 + 1) * 512 + lane * 8];
        #pragma unroll
        for (int ksub = 0; ksub < 4; ++ksub) {
            const bf16x8 bk0 = *(const bf16x8*)&Kf[(ksub * 2 + 0) * 512 + lane * 8];
            const bf16x8 bk1 = *(const bf16x8*)&Kf[(ksub * 2 + 1) * 512 + lane * 8];
            acc_s[ksub] = __builtin_amdgcn_mfma_f32_16x16x32_bf16(
                aq0, bk0, acc_s[ksub], 0, 0, 0);
            acc_s[ksub] = __builtin_amdgcn_mfma_f32_16x16x32_bf16(
                aq1, bk1, acc_s[ksub], 0, 0, 0);
        }

        // Scale + causal mask (diagonal chunk only).
        float sv[4][4];   // [ksub][r]
        #pragma unroll
        for (int ksub = 0; ksub < 4; ++ksub)
            #pragma unroll
            for (int r = 0; r < 4; ++r)
                sv[ksub][r] = acc_s[ksub][r] * 0.125f;
        if (kbase == t0) {
            const int qrow = t0 + w * 16 + quad * 4;   // + r
            #pragma unroll
            for (int ksub = 0; ksub < 4; ++ksub) {
                const int key = kbase + ksub * 16 + l15;
                #pragma unroll
                for (int r = 0; r < 4; ++r)
                    if (key > qrow + r) sv[ksub][r] = -INFINITY;
            }
        }

        // Online softmax; row r stats shared by the 16 lanes of a quad.
        float alpha[4];
        #pragma unroll
        for (int r = 0; r < 4; ++r) {
            float mx = fmaxf(fmaxf(sv[0][r], sv[1][r]), fmaxf(sv[2][r], sv[3][r]));
            mx = fmaxf(mx, __shfl_xor(mx, 1));
            mx = fmaxf(mx, __shfl_xor(mx, 2));
            mx = fmaxf(mx, __shfl_xor(mx, 4));
            mx = fmaxf(mx, __shfl_xor(mx, 8));
            const float m_new = fmaxf(m_run[r], mx);
            alpha[r] = __expf(m_run[r] - m_new);   // first chunk: exp(-inf)=0
            float ps = 0.f;
            #pragma unroll
            for (int ksub = 0; ksub < 4; ++ksub) {
                sv[ksub][r] = __expf(sv[ksub][r] - m_new);
                ps += sv[ksub][r];
            }
            ps += __shfl_xor(ps, 1);
            ps += __shfl_xor(ps, 2);
            ps += __shfl_xor(ps, 4);
            ps += __shfl_xor(ps, 8);
            l_run[r] = l_run[r] * alpha[r] + ps;
            m_run[r] = m_new;
        }

        // Scatter P (bf16) into wave-private A-frag layout.
        #pragma unroll
        for (int ksub = 0; ksub < 4; ++ksub) {
            const int key = ksub * 16 + l15;
            #pragma unroll
            for (int r = 0; r < 4; ++r) {
                const int lp = quad * 4 + r + ((key & 31) >> 3) * 16;
                Pf[(w * 2 + (key >> 5)) * 512 + lp * 8 + (key & 7)] =
                    f2bf(sv[ksub][r]);
            }
        }
        // Same-wave write->read: compiler inserts lgkmcnt wait (no barrier).

        // O = O*alpha + P V  (D[m=q][n=d]); 8 MFMAs.
        #pragma unroll
        for (int n = 0; n < 4; ++n)
            #pragma unroll
            for (int r = 0; r < 4; ++r)
                acc_o[n][r] *= alpha[r];
        const bf16x8 ap0 = *(const bf16x8*)&Pf[(w * 2 + 0) * 512 + lane * 8];
        const bf16x8 ap1 = *(const bf16x8*)&Pf[(w * 2 + 1) * 512 + lane * 8];
        #pragma unroll
        for (int nsub = 0; nsub < 4; ++nsub) {
            const bf16x8 bv0 = *(const bf16x8*)&Vf[(nsub * 2 + 0) * 512 + lane * 8];
            const bf16x8 bv1 = *(const bf16x8*)&Vf[(nsub * 2 + 1) * 512 + lane * 8];
            acc_o[nsub] = __builtin_amdgcn_mfma_f32_16x16x32_bf16(
                ap0, bv0, acc_o[nsub], 0, 0, 0);
            acc_o[nsub] = __builtin_amdgcn_mfma_f32_16x16x32_bf16(
                ap1, bv1, acc_o[nsub], 0, 0, 0);
        }
    }

    // y = O / l (bf16).  C-layout: col=l15 (d), rows quad*4+r.
    float inv[4];
    #pragma unroll
    for (int r = 0; r < 4; ++r) inv[r] = 1.0f / l_run[r];
    #pragma unroll
    for (int nsub = 0; nsub < 4; ++nsub)
        #pragma unroll
        for (int r = 0; r < 4; ++r)
            y[(size_t)(b * kT + t0 + w * 16 + quad * 4 + r) * kC +
              h * kHD + nsub * 16 + l15] = f2bf(acc_o[nsub][r] * inv[r]);
}

extern "C" void kernel_launch(void* const* d_in, const int* in_sizes, int n_in,
                              void* d_out, int out_size, void* d_ws, size_t ws_size,
                              hipStream_t stream) {
    const float* x      = (const float*)d_in[0];
    const float* w_attn = (const float*)d_in[1];
    const float* b_attn = (const float*)d_in[2];
    const float* w_proj = (const float*)d_in[3];
    const float* b_proj = (const float*)d_in[4];
    float* out = (float*)d_out;

    // Workspace (bf16, 64.5 MiB): VT overlays xb (same element count;
    // xb is dead after GEMM1, VT created after GEMM1 — stream-ordered).
    unsigned short* xb     = (unsigned short*)d_ws;           // [8192][768]
    unsigned short* VT     = xb;                              // [96][64][1024]
    unsigned short* wattnT = xb     + (size_t)kM * kC;        // [2304][768]
    unsigned short* wprojT = wattnT + (size_t)k3C * kC;       // [768][768]
    unsigned short* qkv    = wprojT + (size_t)kC * kC;        // [8192][2304]
    unsigned short* yb     = qkv    + (size_t)kM * k3C;       // [8192][768]

    // Pre-passes: cast x; transpose+cast weights to [N][K].
    cvt_bf16_kernel<<<(kM * kC) / (4 * 256), 256, 0, stream>>>(x, xb);
    transpose_cvt_kernel<<<dim3(k3C / 32, kC / 32), 256, 0, stream>>>(
        w_attn, wattnT, kC, k3C);
    transpose_cvt_kernel<<<dim3(kC / 32, kC / 32), 256, 0, stream>>>(
        w_proj, wprojT, kC, kC);

    // 1) QKV projection: xb[8192,768] @ wattnT^T + b_attn -> qkv (bf16)
    gemm_mfma_kernel<true><<<dim3(k3C / 128, kM / 128), 256, 0, stream>>>(
        xb, kC, wattnT, b_attn, qkv, k3C, kC);

    // 1b) V^T pre-pass: qkv V columns -> VT[bh][d][t] (overwrites xb)
    vtrans_kernel<<<kB * kNH * (kT / 64), 256, 0, stream>>>(qkv, VT);

    // 2) MFMA causal attention -> yb (bf16)
    attn_mfma_kernel<<<kB * kNH * (kT / 64), 256, 0, stream>>>(qkv, VT, yb);

    // 3) Output projection: yb @ wprojT^T + b_proj -> out (fp32)
    gemm_mfma_kernel<false><<<dim3(kC / 128, kM / 128), 256, 0, stream>>>(
        yb, kC, wprojT, b_proj, out, kC, kC);
}

// Round 7
// 274.962 us; speedup vs baseline: 6.2191x; 1.0309x over previous
//
#include <hip/hip_runtime.h>

// Problem constants (B,T,C,NH fixed by the reference).
constexpr int kB  = 8;
constexpr int kT  = 1024;
constexpr int kC  = 768;
constexpr int kNH = 12;
constexpr int kHD = 64;          // C/NH
constexpr int kM  = kB * kT;     // 8192 rows
constexpr int k3C = 3 * kC;      // 2304

using bf16x8 = __attribute__((ext_vector_type(8))) __bf16;
using f32x4  = __attribute__((ext_vector_type(4))) float;

__device__ __forceinline__ float bf2f(unsigned short u) {
    union { unsigned int i; float f; } v;
    v.i = ((unsigned int)u) << 16;
    return v.f;
}

// fp32 -> bf16 round-to-nearest-even.
__device__ __forceinline__ unsigned short f2bf(float f) {
    union { float f; unsigned int u; } v; v.f = f;
    unsigned int r = v.u + 0x7fffu + ((v.u >> 16) & 1u);
    return (unsigned short)(r >> 16);
}

// Async global->LDS, 16 B/lane. LDS arg must be the wave-uniform base; HW
// writes lane i at base + i*16 (m104/m108).
__device__ __forceinline__ void async16(const void* g, void* l) {
    __builtin_amdgcn_global_load_lds(
        (__attribute__((address_space(1))) void*)g,
        (__attribute__((address_space(3))) void*)l, 16, 0, 0);
}

// Explicit LDS-DMA drain (round-5 determinism fix — keep).
// imm: vmcnt[3:0]=0 (+[15:14]=0), expcnt[6:4]=7, lgkmcnt[11:8]=15.
__device__ __forceinline__ void wait_vm0() {
    __builtin_amdgcn_s_waitcnt(0x0F70);
}

// ---------------- pre-passes ----------------

// fp32 -> bf16 elementwise (n divisible by 4*256).
__global__ __launch_bounds__(256) void cvt_bf16_kernel(
    const float* __restrict__ in, unsigned short* __restrict__ out)
{
    const int i = blockIdx.x * 256 + threadIdx.x;
    const float4 v = ((const float4*)in)[i];
    ushort4 o;
    o.x = f2bf(v.x); o.y = f2bf(v.y); o.z = f2bf(v.z); o.w = f2bf(v.w);
    ((ushort4*)out)[i] = o;
}

// W[K][N] fp32 -> Wt[N][K] bf16.  Grid (N/32, K/32), block 256 (32x8).
__global__ __launch_bounds__(256) void transpose_cvt_kernel(
    const float* __restrict__ W, unsigned short* __restrict__ Wt, int K, int N)
{
    __shared__ float tile[32][33];
    const int tx = threadIdx.x & 31, ty = threadIdx.x >> 5;
    const int n0 = blockIdx.x * 32, k0 = blockIdx.y * 32;
    #pragma unroll
    for (int i = 0; i < 4; ++i)
        tile[ty + i * 8][tx] = W[(size_t)(k0 + ty + i * 8) * N + n0 + tx];
    __syncthreads();
    #pragma unroll
    for (int i = 0; i < 4; ++i)
        Wt[(size_t)(n0 + ty + i * 8) * K + k0 + tx] = f2bf(tile[tx][ty + i * 8]);
}

// V columns of qkv -> VT[bh][d][t] (bf16).  One block = 64t x 64d of one
// (b,h).  Grid 96*16.
__global__ __launch_bounds__(256) void vtrans_kernel(
    const unsigned short* __restrict__ qkv, unsigned short* __restrict__ VT)
{
    __shared__ unsigned short tile[64][72];   // 144 B rows (16B-aligned)
    const int tid = threadIdx.x;
    const int bh = blockIdx.x >> 4;
    const int b = bh / kNH, h = bh % kNH;
    const int tt = (blockIdx.x & 15) * 64;
    const int row = tid >> 2;
    const int c0  = (tid & 3) * 16;
    const unsigned short* src =
        qkv + (size_t)(b * kT + tt + row) * k3C + 2 * kC + h * kHD + c0;
    *(uint4*)&tile[row][c0]     = *(const uint4*)src;
    *(uint4*)&tile[row][c0 + 8] = *(const uint4*)(src + 8);
    __syncthreads();
    const int d  = tid >> 2;
    const int t8 = (tid & 3) * 16;
    unsigned short tmp[16];
    #pragma unroll
    for (int i = 0; i < 16; ++i) tmp[i] = tile[t8 + i][d];
    unsigned short* dst = VT + ((size_t)bh * kHD + d) * kT + tt + t8;
    *(uint4*)dst       = *(uint4*)&tmp[0];
    *(uint4*)(dst + 8) = *(uint4*)&tmp[8];
}

// ---------------- MFMA GEMM ----------------
// out[M,N] = A[M,K](bf16, row stride lda) @ Bt[N,K](bf16)^T + bias(fp32).
// 128x128 tile, BK=64, 256 threads (4 waves, 2x2 of 64x64 each).
template<bool OUT_BF16>
__global__ __launch_bounds__(256) void gemm_mfma_kernel(
    const unsigned short* __restrict__ A, int lda,
    const unsigned short* __restrict__ Bt,
    const float* __restrict__ bias,
    void* __restrict__ outv, int N, int K)
{
    alignas(16) __shared__ unsigned short As[16 * 512];  // 16 KB
    alignas(16) __shared__ unsigned short Bs[16 * 512];  // 16 KB

    const int tid  = threadIdx.x;
    const int w    = tid >> 6;
    const int lane = tid & 63;
    const int wr = w >> 1, wc = w & 1;
    const int m0 = blockIdx.y * 128, n0 = blockIdx.x * 128;

    const int fr = lane & 15;            // row within 16-row subtile
    const int fk = (lane >> 4) * 8;      // k offset within 32-k subtile

    f32x4 acc[4][4];
    #pragma unroll
    for (int i = 0; i < 4; ++i)
        #pragma unroll
        for (int j = 0; j < 4; ++j) {
            f32x4 z = {0.f, 0.f, 0.f, 0.f};
            acc[i][j] = z;
        }

    for (int kt = 0; kt < K; kt += 64) {
        #pragma unroll
        for (int t = 0; t < 4; ++t) {
            const int fa = w * 4 + t;            // fragment tile 0..15
            const int ki = fa >> 3, si = fa & 7; // k-subtile, m/n-subtile
            const unsigned short* ga =
                A + (size_t)(m0 + si * 16 + fr) * lda + kt + ki * 32 + fk;
            async16(ga, &As[fa * 512]);          // wave-uniform LDS base
            const unsigned short* gb =
                Bt + (size_t)(n0 + si * 16 + fr) * K + kt + ki * 32 + fk;
            async16(gb, &Bs[fa * 512]);
        }
        wait_vm0();
        __syncthreads();

        #pragma unroll
        for (int ki = 0; ki < 2; ++ki) {
            bf16x8 a[4], b[4];
            #pragma unroll
            for (int i = 0; i < 4; ++i)
                a[i] = *(const bf16x8*)&As[(ki * 8 + wr * 4 + i) * 512 + lane * 8];
            #pragma unroll
            for (int j = 0; j < 4; ++j)
                b[j] = *(const bf16x8*)&Bs[(ki * 8 + wc * 4 + j) * 512 + lane * 8];
            #pragma unroll
            for (int i = 0; i < 4; ++i)
                #pragma unroll
                for (int j = 0; j < 4; ++j)
                    acc[i][j] = __builtin_amdgcn_mfma_f32_16x16x32_bf16(
                        a[i], b[j], acc[i][j], 0, 0, 0);
        }
        __syncthreads();
    }

    // Epilogue.  C/D: col = lane&15, row = (lane>>4)*4 + reg.
    const int quad  = lane >> 4;
    const int col16 = lane & 15;
    float biasv[4];
    #pragma unroll
    for (int j = 0; j < 4; ++j)
        biasv[j] = bias[n0 + wc * 64 + j * 16 + col16];

    #pragma unroll
    for (int i = 0; i < 4; ++i) {
        #pragma unroll
        for (int r = 0; r < 4; ++r) {
            const int row = m0 + wr * 64 + i * 16 + quad * 4 + r;
            #pragma unroll
            for (int j = 0; j < 4; ++j) {
                const int col = n0 + wc * 64 + j * 16 + col16;
                const float v = acc[i][j][r] + biasv[j];
                if (OUT_BF16)
                    ((unsigned short*)outv)[(size_t)row * N + col] = f2bf(v);
                else
                    ((float*)outv)[(size_t)row * N + col] = v;
            }
        }
    }
}

// ---------------- MFMA flash attention (double-buffered) ----------------
// One block = 64 query rows of one (b,h); 4 waves; wave w owns q-subtile w.
// Round-7 changes vs round-6:
//  * K/V LDS double-buffered: chunk c+1's async16 staging is issued right
//    after the top-of-iter barrier, overlapping chunk c's compute (the
//    round-6 profile showed latency-bound: 4600 cyc/chunk vs ~600 issue).
//    WAR-safe: buffer (c+1)&1 was last read at chunk c-1, which every wave
//    completed before passing this iteration's barrier.
//  * Q hoisted to registers (staged once via Pf, wave-private, no barrier);
//    removes 2 ds_read_b128/chunk and the Qf array.
//  * One barrier per chunk (was two).
// LDS 40 KB -> 4 blocks/CU.
__global__ __launch_bounds__(256) void attn_mfma_kernel(
    const unsigned short* __restrict__ qkv,
    const unsigned short* __restrict__ VT,     // [96][64][1024]
    unsigned short* __restrict__ y)            // [8192][768]
{
    alignas(16) __shared__ unsigned short Kf[2][8 * 512];  // 16 KB
    alignas(16) __shared__ unsigned short Vf[2][8 * 512];  // 16 KB
    alignas(16) __shared__ unsigned short Pf[8 * 512];     // 8 KB, wave-private

    const int tid  = threadIdx.x;
    const int w    = tid >> 6;
    const int lane = tid & 63;
    const int quad = lane >> 4, l15 = lane & 15;
    const int bh = blockIdx.x >> 4;
    const int b  = bh / kNH, h = bh % kNH;
    const int t0 = (15 - (blockIdx.x & 15)) * 64;   // heavy q-tiles first
    const int nchunks = t0 / 64 + 1;

    // Stage K frags (ksub=w) and V^T frags (nsub=w) for chunk kbase.
    auto stage = [&](int bufi, int kbase) {
        const unsigned short* gk = qkv +
            (size_t)(b * kT + kbase + w * 16 + l15) * k3C + kC + h * kHD + quad * 8;
        async16(gk,      &Kf[bufi][(w * 2 + 0) * 512]);
        async16(gk + 32, &Kf[bufi][(w * 2 + 1) * 512]);
        const unsigned short* gv = VT +
            ((size_t)bh * kHD + w * 16 + l15) * kT + kbase + quad * 8;
        async16(gv,      &Vf[bufi][(w * 2 + 0) * 512]);
        async16(gv + 32, &Vf[bufi][(w * 2 + 1) * 512]);
    };

    stage(0, 0);
    // Q staged once through Pf (wave-private region), hoisted to registers.
    {
        const unsigned short* g0 =
            qkv + (size_t)(b * kT + t0 + w * 16 + l15) * k3C + h * kHD + quad * 8;
        async16(g0,      &Pf[(w * 2 + 0) * 512]);
        async16(g0 + 32, &Pf[(w * 2 + 1) * 512]);
    }
    wait_vm0();   // own-wave DMA drained; Pf region is wave-private
    const bf16x8 aq0 = *(const bf16x8*)&Pf[(w * 2 + 0) * 512 + lane * 8];
    const bf16x8 aq1 = *(const bf16x8*)&Pf[(w * 2 + 1) * 512 + lane * 8];

    float m_run[4], l_run[4];
    f32x4 acc_o[4];
    #pragma unroll
    for (int r = 0; r < 4; ++r) { m_run[r] = -INFINITY; l_run[r] = 0.f; }
    #pragma unroll
    for (int n = 0; n < 4; ++n) {
        f32x4 z = {0.f, 0.f, 0.f, 0.f};
        acc_o[n] = z;
    }

    for (int c = 0; c < nchunks; ++c) {
        const int kbase = c * 64;
        const int buf = c & 1;
        wait_vm0();        // drain stage(c) (issued last iteration / preloop)
        __syncthreads();   // all waves' parts visible; prev buffer reads done
        if (c + 1 < nchunks) stage(1 - buf, kbase + 64);  // prefetch, overlaps

        // S = Q K^T  (D[m=q][n=key]); 8 MFMAs.
        f32x4 acc_s[4];
        #pragma unroll
        for (int k = 0; k < 4; ++k) {
            f32x4 z = {0.f, 0.f, 0.f, 0.f};
            acc_s[k] = z;
        }
        #pragma unroll
        for (int ksub = 0; ksub < 4; ++ksub) {
            const bf16x8 bk0 =
                *(const bf16x8*)&Kf[buf][(ksub * 2 + 0) * 512 + lane * 8];
            const bf16x8 bk1 =
                *(const bf16x8*)&Kf[buf][(ksub * 2 + 1) * 512 + lane * 8];
            acc_s[ksub] = __builtin_amdgcn_mfma_f32_16x16x32_bf16(
                aq0, bk0, acc_s[ksub], 0, 0, 0);
            acc_s[ksub] = __builtin_amdgcn_mfma_f32_16x16x32_bf16(
                aq1, bk1, acc_s[ksub], 0, 0, 0);
        }

        // Scale + causal mask (diagonal chunk only).
        float sv[4][4];   // [ksub][r]
        #pragma unroll
        for (int ksub = 0; ksub < 4; ++ksub)
            #pragma unroll
            for (int r = 0; r < 4; ++r)
                sv[ksub][r] = acc_s[ksub][r] * 0.125f;
        if (kbase == t0) {
            const int qrow = t0 + w * 16 + quad * 4;   // + r
            #pragma unroll
            for (int ksub = 0; ksub < 4; ++ksub) {
                const int key = kbase + ksub * 16 + l15;
                #pragma unroll
                for (int r = 0; r < 4; ++r)
                    if (key > qrow + r) sv[ksub][r] = -INFINITY;
            }
        }

        // Online softmax; row r stats shared by the 16 lanes of a quad.
        float alpha[4];
        #pragma unroll
        for (int r = 0; r < 4; ++r) {
            float mx = fmaxf(fmaxf(sv[0][r], sv[1][r]), fmaxf(sv[2][r], sv[3][r]));
            mx = fmaxf(mx, __shfl_xor(mx, 1));
            mx = fmaxf(mx, __shfl_xor(mx, 2));
            mx = fmaxf(mx, __shfl_xor(mx, 4));
            mx = fmaxf(mx, __shfl_xor(mx, 8));
            const float m_new = fmaxf(m_run[r], mx);
            alpha[r] = __expf(m_run[r] - m_new);   // first chunk: exp(-inf)=0
            float ps = 0.f;
            #pragma unroll
            for (int ksub = 0; ksub < 4; ++ksub) {
                sv[ksub][r] = __expf(sv[ksub][r] - m_new);
                ps += sv[ksub][r];
            }
            ps += __shfl_xor(ps, 1);
            ps += __shfl_xor(ps, 2);
            ps += __shfl_xor(ps, 4);
            ps += __shfl_xor(ps, 8);
            l_run[r] = l_run[r] * alpha[r] + ps;
            m_run[r] = m_new;
        }

        // Scatter P (bf16) into wave-private A-frag layout (DS ops within a
        // wave are ordered, so no barrier between this write and the read).
        #pragma unroll
        for (int ksub = 0; ksub < 4; ++ksub) {
            const int key = ksub * 16 + l15;
            #pragma unroll
            for (int r = 0; r < 4; ++r) {
                const int lp = quad * 4 + r + ((key & 31) >> 3) * 16;
                Pf[(w * 2 + (key >> 5)) * 512 + lp * 8 + (key & 7)] =
                    f2bf(sv[ksub][r]);
            }
        }

        // O = O*alpha + P V  (D[m=q][n=d]); 8 MFMAs.
        #pragma unroll
        for (int n = 0; n < 4; ++n)
            #pragma unroll
            for (int r = 0; r < 4; ++r)
                acc_o[n][r] *= alpha[r];
        const bf16x8 ap0 = *(const bf16x8*)&Pf[(w * 2 + 0) * 512 + lane * 8];
        const bf16x8 ap1 = *(const bf16x8*)&Pf[(w * 2 + 1) * 512 + lane * 8];
        #pragma unroll
        for (int nsub = 0; nsub < 4; ++nsub) {
            const bf16x8 bv0 =
                *(const bf16x8*)&Vf[buf][(nsub * 2 + 0) * 512 + lane * 8];
            const bf16x8 bv1 =
                *(const bf16x8*)&Vf[buf][(nsub * 2 + 1) * 512 + lane * 8];
            acc_o[nsub] = __builtin_amdgcn_mfma_f32_16x16x32_bf16(
                ap0, bv0, acc_o[nsub], 0, 0, 0);
            acc_o[nsub] = __builtin_amdgcn_mfma_f32_16x16x32_bf16(
                ap1, bv1, acc_o[nsub], 0, 0, 0);
        }
    }

    // y = O / l (bf16).  C-layout: col=l15 (d), rows quad*4+r.
    float inv[4];
    #pragma unroll
    for (int r = 0; r < 4; ++r) inv[r] = 1.0f / l_run[r];
    #pragma unroll
    for (int nsub = 0; nsub < 4; ++nsub)
        #pragma unroll
        for (int r = 0; r < 4; ++r)
            y[(size_t)(b * kT + t0 + w * 16 + quad * 4 + r) * kC +
              h * kHD + nsub * 16 + l15] = f2bf(acc_o[nsub][r] * inv[r]);
}

extern "C" void kernel_launch(void* const* d_in, const int* in_sizes, int n_in,
                              void* d_out, int out_size, void* d_ws, size_t ws_size,
                              hipStream_t stream) {
    const float* x      = (const float*)d_in[0];
    const float* w_attn = (const float*)d_in[1];
    const float* b_attn = (const float*)d_in[2];
    const float* w_proj = (const float*)d_in[3];
    const float* b_proj = (const float*)d_in[4];
    float* out = (float*)d_out;

    // Workspace (bf16, 64.5 MiB): VT overlays xb (same element count;
    // xb is dead after GEMM1, VT created after GEMM1 — stream-ordered).
    unsigned short* xb     = (unsigned short*)d_ws;           // [8192][768]
    unsigned short* VT     = xb;                              // [96][64][1024]
    unsigned short* wattnT = xb     + (size_t)kM * kC;        // [2304][768]
    unsigned short* wprojT = wattnT + (size_t)k3C * kC;       // [768][768]
    unsigned short* qkv    = wprojT + (size_t)kC * kC;        // [8192][2304]
    unsigned short* yb     = qkv    + (size_t)kM * k3C;       // [8192][768]

    // Pre-passes: cast x; transpose+cast weights to [N][K].
    cvt_bf16_kernel<<<(kM * kC) / (4 * 256), 256, 0, stream>>>(x, xb);
    transpose_cvt_kernel<<<dim3(k3C / 32, kC / 32), 256, 0, stream>>>(
        w_attn, wattnT, kC, k3C);
    transpose_cvt_kernel<<<dim3(kC / 32, kC / 32), 256, 0, stream>>>(
        w_proj, wprojT, kC, kC);

    // 1) QKV projection: xb[8192,768] @ wattnT^T + b_attn -> qkv (bf16)
    gemm_mfma_kernel<true><<<dim3(k3C / 128, kM / 128), 256, 0, stream>>>(
        xb, kC, wattnT, b_attn, qkv, k3C, kC);

    // 1b) V^T pre-pass: qkv V columns -> VT[bh][d][t] (overwrites xb)
    vtrans_kernel<<<kB * kNH * (kT / 64), 256, 0, stream>>>(qkv, VT);

    // 2) MFMA causal attention -> yb (bf16)
    attn_mfma_kernel<<<kB * kNH * (kT / 64), 256, 0, stream>>>(qkv, VT, yb);

    // 3) Output projection: yb @ wprojT^T + b_proj -> out (fp32)
    gemm_mfma_kernel<false><<<dim3(kC / 128, kM / 128), 256, 0, stream>>>(
        yb, kC, wprojT, b_proj, out, kC, kC);
}

// Round 8
// 249.333 us; speedup vs baseline: 6.8583x; 1.1028x over previous
//
#include <hip/hip_runtime.h>

// Problem constants (B,T,C,NH fixed by the reference).
constexpr int kB  = 8;
constexpr int kT  = 1024;
constexpr int kC  = 768;
constexpr int kNH = 12;
constexpr int kHD = 64;          // C/NH
constexpr int kM  = kB * kT;     // 8192 rows
constexpr int k3C = 3 * kC;      // 2304

using bf16x8 = __attribute__((ext_vector_type(8))) __bf16;
using f32x4  = __attribute__((ext_vector_type(4))) float;

__device__ __forceinline__ float bf2f(unsigned short u) {
    union { unsigned int i; float f; } v;
    v.i = ((unsigned int)u) << 16;
    return v.f;
}

// fp32 -> bf16 round-to-nearest-even.
__device__ __forceinline__ unsigned short f2bf(float f) {
    union { float f; unsigned int u; } v; v.f = f;
    unsigned int r = v.u + 0x7fffu + ((v.u >> 16) & 1u);
    return (unsigned short)(r >> 16);
}

// Async global->LDS, 16 B/lane. LDS arg must be the wave-uniform base; HW
// writes lane i at base + i*16 (m104/m108).
__device__ __forceinline__ void async16(const void* g, void* l) {
    __builtin_amdgcn_global_load_lds(
        (__attribute__((address_space(1))) void*)g,
        (__attribute__((address_space(3))) void*)l, 16, 0, 0);
}

// Explicit LDS-DMA drain (round-5 determinism fix — keep).
// imm: vmcnt[3:0]=0 (+[15:14]=0), expcnt[6:4]=7, lgkmcnt[11:8]=15.
__device__ __forceinline__ void wait_vm0() {
    __builtin_amdgcn_s_waitcnt(0x0F70);
}

// ---------------- pre-passes ----------------

// fp32 -> bf16 elementwise (n divisible by 4*256).
__global__ __launch_bounds__(256) void cvt_bf16_kernel(
    const float* __restrict__ in, unsigned short* __restrict__ out)
{
    const int i = blockIdx.x * 256 + threadIdx.x;
    const float4 v = ((const float4*)in)[i];
    ushort4 o;
    o.x = f2bf(v.x); o.y = f2bf(v.y); o.z = f2bf(v.z); o.w = f2bf(v.w);
    ((ushort4*)out)[i] = o;
}

// W[K][N] fp32 -> Wt[N][K] bf16.  Grid (N/32, K/32), block 256 (32x8).
__global__ __launch_bounds__(256) void transpose_cvt_kernel(
    const float* __restrict__ W, unsigned short* __restrict__ Wt, int K, int N)
{
    __shared__ float tile[32][33];
    const int tx = threadIdx.x & 31, ty = threadIdx.x >> 5;
    const int n0 = blockIdx.x * 32, k0 = blockIdx.y * 32;
    #pragma unroll
    for (int i = 0; i < 4; ++i)
        tile[ty + i * 8][tx] = W[(size_t)(k0 + ty + i * 8) * N + n0 + tx];
    __syncthreads();
    #pragma unroll
    for (int i = 0; i < 4; ++i)
        Wt[(size_t)(n0 + ty + i * 8) * K + k0 + tx] = f2bf(tile[tx][ty + i * 8]);
}

// V columns of qkv -> VT[bh][d][t] (bf16).  One block = 64t x 64d of one
// (b,h).  Grid 96*16.
__global__ __launch_bounds__(256) void vtrans_kernel(
    const unsigned short* __restrict__ qkv, unsigned short* __restrict__ VT)
{
    __shared__ unsigned short tile[64][72];   // 144 B rows (16B-aligned)
    const int tid = threadIdx.x;
    const int bh = blockIdx.x >> 4;
    const int b = bh / kNH, h = bh % kNH;
    const int tt = (blockIdx.x & 15) * 64;
    const int row = tid >> 2;
    const int c0  = (tid & 3) * 16;
    const unsigned short* src =
        qkv + (size_t)(b * kT + tt + row) * k3C + 2 * kC + h * kHD + c0;
    *(uint4*)&tile[row][c0]     = *(const uint4*)src;
    *(uint4*)&tile[row][c0 + 8] = *(const uint4*)(src + 8);
    __syncthreads();
    const int d  = tid >> 2;
    const int t8 = (tid & 3) * 16;
    unsigned short tmp[16];
    #pragma unroll
    for (int i = 0; i < 16; ++i) tmp[i] = tile[t8 + i][d];
    unsigned short* dst = VT + ((size_t)bh * kHD + d) * kT + tt + t8;
    *(uint4*)dst       = *(uint4*)&tmp[0];
    *(uint4*)(dst + 8) = *(uint4*)&tmp[8];
}

// ---------------- MFMA GEMM ----------------
// out[M,N] = A[M,K](bf16, row stride lda) @ Bt[N,K](bf16)^T + bias(fp32).
// 128x128 tile, BK=64, 256 threads (4 waves, 2x2 of 64x64 each).
template<bool OUT_BF16>
__global__ __launch_bounds__(256) void gemm_mfma_kernel(
    const unsigned short* __restrict__ A, int lda,
    const unsigned short* __restrict__ Bt,
    const float* __restrict__ bias,
    void* __restrict__ outv, int N, int K)
{
    alignas(16) __shared__ unsigned short As[16 * 512];  // 16 KB
    alignas(16) __shared__ unsigned short Bs[16 * 512];  // 16 KB

    const int tid  = threadIdx.x;
    const int w    = tid >> 6;
    const int lane = tid & 63;
    const int wr = w >> 1, wc = w & 1;
    const int m0 = blockIdx.y * 128, n0 = blockIdx.x * 128;

    const int fr = lane & 15;            // row within 16-row subtile
    const int fk = (lane >> 4) * 8;      // k offset within 32-k subtile

    f32x4 acc[4][4];
    #pragma unroll
    for (int i = 0; i < 4; ++i)
        #pragma unroll
        for (int j = 0; j < 4; ++j) {
            f32x4 z = {0.f, 0.f, 0.f, 0.f};
            acc[i][j] = z;
        }

    for (int kt = 0; kt < K; kt += 64) {
        #pragma unroll
        for (int t = 0; t < 4; ++t) {
            const int fa = w * 4 + t;            // fragment tile 0..15
            const int ki = fa >> 3, si = fa & 7; // k-subtile, m/n-subtile
            const unsigned short* ga =
                A + (size_t)(m0 + si * 16 + fr) * lda + kt + ki * 32 + fk;
            async16(ga, &As[fa * 512]);          // wave-uniform LDS base
            const unsigned short* gb =
                Bt + (size_t)(n0 + si * 16 + fr) * K + kt + ki * 32 + fk;
            async16(gb, &Bs[fa * 512]);
        }
        wait_vm0();
        __syncthreads();

        #pragma unroll
        for (int ki = 0; ki < 2; ++ki) {
            bf16x8 a[4], b[4];
            #pragma unroll
            for (int i = 0; i < 4; ++i)
                a[i] = *(const bf16x8*)&As[(ki * 8 + wr * 4 + i) * 512 + lane * 8];
            #pragma unroll
            for (int j = 0; j < 4; ++j)
                b[j] = *(const bf16x8*)&Bs[(ki * 8 + wc * 4 + j) * 512 + lane * 8];
            #pragma unroll
            for (int i = 0; i < 4; ++i)
                #pragma unroll
                for (int j = 0; j < 4; ++j)
                    acc[i][j] = __builtin_amdgcn_mfma_f32_16x16x32_bf16(
                        a[i], b[j], acc[i][j], 0, 0, 0);
        }
        __syncthreads();
    }

    // Epilogue.  C/D: col = lane&15, row = (lane>>4)*4 + reg.
    const int quad  = lane >> 4;
    const int col16 = lane & 15;
    float biasv[4];
    #pragma unroll
    for (int j = 0; j < 4; ++j)
        biasv[j] = bias[n0 + wc * 64 + j * 16 + col16];

    #pragma unroll
    for (int i = 0; i < 4; ++i) {
        #pragma unroll
        for (int r = 0; r < 4; ++r) {
            const int row = m0 + wr * 64 + i * 16 + quad * 4 + r;
            #pragma unroll
            for (int j = 0; j < 4; ++j) {
                const int col = n0 + wc * 64 + j * 16 + col16;
                const float v = acc[i][j][r] + biasv[j];
                if (OUT_BF16)
                    ((unsigned short*)outv)[(size_t)row * N + col] = f2bf(v);
                else
                    ((float*)outv)[(size_t)row * N + col] = v;
            }
        }
    }
}

// ---------------- MFMA flash attention (paired q-tiles) ----------------
// Round-8 change: WORK-UNIFORM BLOCKS. Causal chunk counts pair perfectly:
// q-tile u costs u+1 chunks, tile 15-u costs 16-u -> every pair sums to 17.
// One block = q-tiles (15-pid, pid) of one (b,h), processed as two
// sequential phases sharing the round-7 body (K/V dbuf prefetch, reg-Q,
// reg-softmax). Grid 96*8=768 uniform blocks = 3 resident blocks/CU with
// no drain tail (round-7 profile: occupancy 19%, duration dominated by the
// 96 heavy blocks finishing alone).
__global__ __launch_bounds__(256) void attn_mfma_kernel(
    const unsigned short* __restrict__ qkv,
    const unsigned short* __restrict__ VT,     // [96][64][1024]
    unsigned short* __restrict__ y)            // [8192][768]
{
    alignas(16) __shared__ unsigned short Kf[2][8 * 512];  // 16 KB
    alignas(16) __shared__ unsigned short Vf[2][8 * 512];  // 16 KB
    alignas(16) __shared__ unsigned short Pf[8 * 512];     // 8 KB, wave-private

    const int tid  = threadIdx.x;
    const int w    = tid >> 6;
    const int lane = tid & 63;
    const int quad = lane >> 4, l15 = lane & 15;
    const int bh  = blockIdx.x >> 3;
    const int b   = bh / kNH, h = bh % kNH;
    const int pid = blockIdx.x & 7;

    // Stage K frags (ksub=w) and V^T frags (nsub=w) for chunk kbase.
    auto stage = [&](int bufi, int kbase) {
        const unsigned short* gk = qkv +
            (size_t)(b * kT + kbase + w * 16 + l15) * k3C + kC + h * kHD + quad * 8;
        async16(gk,      &Kf[bufi][(w * 2 + 0) * 512]);
        async16(gk + 32, &Kf[bufi][(w * 2 + 1) * 512]);
        const unsigned short* gv = VT +
            ((size_t)bh * kHD + w * 16 + l15) * kT + kbase + quad * 8;
        async16(gv,      &Vf[bufi][(w * 2 + 0) * 512]);
        async16(gv + 32, &Vf[bufi][(w * 2 + 1) * 512]);
    };

    #pragma unroll 1
    for (int phase = 0; phase < 2; ++phase) {
        const int t0 = (phase == 0 ? (15 - pid) : pid) * 64;  // heavy first
        const int nchunks = t0 / 64 + 1;

        // WAR: all waves done reading K/V buffers from the previous phase
        // before we restage buffer 0. (Harmless extra barrier in phase 0.)
        __syncthreads();
        stage(0, 0);
        // Q staged once through Pf (wave-private region) -> registers.
        {
            const unsigned short* g0 = qkv +
                (size_t)(b * kT + t0 + w * 16 + l15) * k3C + h * kHD + quad * 8;
            async16(g0,      &Pf[(w * 2 + 0) * 512]);
            async16(g0 + 32, &Pf[(w * 2 + 1) * 512]);
        }
        wait_vm0();   // own-wave DMA drained; Pf region is wave-private
        const bf16x8 aq0 = *(const bf16x8*)&Pf[(w * 2 + 0) * 512 + lane * 8];
        const bf16x8 aq1 = *(const bf16x8*)&Pf[(w * 2 + 1) * 512 + lane * 8];

        float m_run[4], l_run[4];
        f32x4 acc_o[4];
        #pragma unroll
        for (int r = 0; r < 4; ++r) { m_run[r] = -INFINITY; l_run[r] = 0.f; }
        #pragma unroll
        for (int n = 0; n < 4; ++n) {
            f32x4 z = {0.f, 0.f, 0.f, 0.f};
            acc_o[n] = z;
        }

        for (int c = 0; c < nchunks; ++c) {
            const int kbase = c * 64;
            const int buf = c & 1;
            wait_vm0();        // drain stage(c) (issued prev iter / phase top)
            __syncthreads();   // all waves' parts visible; prev buffer free
            if (c + 1 < nchunks) stage(1 - buf, kbase + 64);  // prefetch

            // S = Q K^T  (D[m=q][n=key]); 8 MFMAs.
            f32x4 acc_s[4];
            #pragma unroll
            for (int k = 0; k < 4; ++k) {
                f32x4 z = {0.f, 0.f, 0.f, 0.f};
                acc_s[k] = z;
            }
            #pragma unroll
            for (int ksub = 0; ksub < 4; ++ksub) {
                const bf16x8 bk0 =
                    *(const bf16x8*)&Kf[buf][(ksub * 2 + 0) * 512 + lane * 8];
                const bf16x8 bk1 =
                    *(const bf16x8*)&Kf[buf][(ksub * 2 + 1) * 512 + lane * 8];
                acc_s[ksub] = __builtin_amdgcn_mfma_f32_16x16x32_bf16(
                    aq0, bk0, acc_s[ksub], 0, 0, 0);
                acc_s[ksub] = __builtin_amdgcn_mfma_f32_16x16x32_bf16(
                    aq1, bk1, acc_s[ksub], 0, 0, 0);
            }

            // Scale + causal mask (diagonal chunk only).
            float sv[4][4];   // [ksub][r]
            #pragma unroll
            for (int ksub = 0; ksub < 4; ++ksub)
                #pragma unroll
                for (int r = 0; r < 4; ++r)
                    sv[ksub][r] = acc_s[ksub][r] * 0.125f;
            if (kbase == t0) {
                const int qrow = t0 + w * 16 + quad * 4;   // + r
                #pragma unroll
                for (int ksub = 0; ksub < 4; ++ksub) {
                    const int key = kbase + ksub * 16 + l15;
                    #pragma unroll
                    for (int r = 0; r < 4; ++r)
                        if (key > qrow + r) sv[ksub][r] = -INFINITY;
                }
            }

            // Online softmax; row r stats shared by the 16 lanes of a quad.
            float alpha[4];
            #pragma unroll
            for (int r = 0; r < 4; ++r) {
                float mx = fmaxf(fmaxf(sv[0][r], sv[1][r]),
                                 fmaxf(sv[2][r], sv[3][r]));
                mx = fmaxf(mx, __shfl_xor(mx, 1));
                mx = fmaxf(mx, __shfl_xor(mx, 2));
                mx = fmaxf(mx, __shfl_xor(mx, 4));
                mx = fmaxf(mx, __shfl_xor(mx, 8));
                const float m_new = fmaxf(m_run[r], mx);
                alpha[r] = __expf(m_run[r] - m_new);  // 1st chunk: exp(-inf)=0
                float ps = 0.f;
                #pragma unroll
                for (int ksub = 0; ksub < 4; ++ksub) {
                    sv[ksub][r] = __expf(sv[ksub][r] - m_new);
                    ps += sv[ksub][r];
                }
                ps += __shfl_xor(ps, 1);
                ps += __shfl_xor(ps, 2);
                ps += __shfl_xor(ps, 4);
                ps += __shfl_xor(ps, 8);
                l_run[r] = l_run[r] * alpha[r] + ps;
                m_run[r] = m_new;
            }

            // Scatter P (bf16) into wave-private A-frag layout (same-wave
            // DS ordering: no barrier between this write and the read).
            #pragma unroll
            for (int ksub = 0; ksub < 4; ++ksub) {
                const int key = ksub * 16 + l15;
                #pragma unroll
                for (int r = 0; r < 4; ++r) {
                    const int lp = quad * 4 + r + ((key & 31) >> 3) * 16;
                    Pf[(w * 2 + (key >> 5)) * 512 + lp * 8 + (key & 7)] =
                        f2bf(sv[ksub][r]);
                }
            }

            // O = O*alpha + P V  (D[m=q][n=d]); 8 MFMAs.
            #pragma unroll
            for (int n = 0; n < 4; ++n)
                #pragma unroll
                for (int r = 0; r < 4; ++r)
                    acc_o[n][r] *= alpha[r];
            const bf16x8 ap0 = *(const bf16x8*)&Pf[(w * 2 + 0) * 512 + lane * 8];
            const bf16x8 ap1 = *(const bf16x8*)&Pf[(w * 2 + 1) * 512 + lane * 8];
            #pragma unroll
            for (int nsub = 0; nsub < 4; ++nsub) {
                const bf16x8 bv0 =
                    *(const bf16x8*)&Vf[buf][(nsub * 2 + 0) * 512 + lane * 8];
                const bf16x8 bv1 =
                    *(const bf16x8*)&Vf[buf][(nsub * 2 + 1) * 512 + lane * 8];
                acc_o[nsub] = __builtin_amdgcn_mfma_f32_16x16x32_bf16(
                    ap0, bv0, acc_o[nsub], 0, 0, 0);
                acc_o[nsub] = __builtin_amdgcn_mfma_f32_16x16x32_bf16(
                    ap1, bv1, acc_o[nsub], 0, 0, 0);
            }
        }

        // y = O / l (bf16).  C-layout: col=l15 (d), rows quad*4+r.
        float inv[4];
        #pragma unroll
        for (int r = 0; r < 4; ++r) inv[r] = 1.0f / l_run[r];
        #pragma unroll
        for (int nsub = 0; nsub < 4; ++nsub)
            #pragma unroll
            for (int r = 0; r < 4; ++r)
                y[(size_t)(b * kT + t0 + w * 16 + quad * 4 + r) * kC +
                  h * kHD + nsub * 16 + l15] = f2bf(acc_o[nsub][r] * inv[r]);
    }
}

extern "C" void kernel_launch(void* const* d_in, const int* in_sizes, int n_in,
                              void* d_out, int out_size, void* d_ws, size_t ws_size,
                              hipStream_t stream) {
    const float* x      = (const float*)d_in[0];
    const float* w_attn = (const float*)d_in[1];
    const float* b_attn = (const float*)d_in[2];
    const float* w_proj = (const float*)d_in[3];
    const float* b_proj = (const float*)d_in[4];
    float* out = (float*)d_out;

    // Workspace (bf16, 64.5 MiB): VT overlays xb (same element count;
    // xb is dead after GEMM1, VT created after GEMM1 — stream-ordered).
    unsigned short* xb     = (unsigned short*)d_ws;           // [8192][768]
    unsigned short* VT     = xb;                              // [96][64][1024]
    unsigned short* wattnT = xb     + (size_t)kM * kC;        // [2304][768]
    unsigned short* wprojT = wattnT + (size_t)k3C * kC;       // [768][768]
    unsigned short* qkv    = wprojT + (size_t)kC * kC;        // [8192][2304]
    unsigned short* yb     = qkv    + (size_t)kM * k3C;       // [8192][768]

    // Pre-passes: cast x; transpose+cast weights to [N][K].
    cvt_bf16_kernel<<<(kM * kC) / (4 * 256), 256, 0, stream>>>(x, xb);
    transpose_cvt_kernel<<<dim3(k3C / 32, kC / 32), 256, 0, stream>>>(
        w_attn, wattnT, kC, k3C);
    transpose_cvt_kernel<<<dim3(kC / 32, kC / 32), 256, 0, stream>>>(
        w_proj, wprojT, kC, kC);

    // 1) QKV projection: xb[8192,768] @ wattnT^T + b_attn -> qkv (bf16)
    gemm_mfma_kernel<true><<<dim3(k3C / 128, kM / 128), 256, 0, stream>>>(
        xb, kC, wattnT, b_attn, qkv, k3C, kC);

    // 1b) V^T pre-pass: qkv V columns -> VT[bh][d][t] (overwrites xb)
    vtrans_kernel<<<kB * kNH * (kT / 64), 256, 0, stream>>>(qkv, VT);

    // 2) MFMA causal attention (paired q-tiles, uniform blocks) -> yb
    attn_mfma_kernel<<<kB * kNH * 8, 256, 0, stream>>>(qkv, VT, yb);

    // 3) Output projection: yb @ wprojT^T + b_proj -> out (fp32)
    gemm_mfma_kernel<false><<<dim3(kC / 128, kM / 128), 256, 0, stream>>>(
        yb, kC, wprojT, b_proj, out, kC, kC);
}